// Round 1
// baseline (598.613 us; speedup 1.0000x reference)
//
#include <hip/hip_runtime.h>

#define IN_DIM 128
#define HID    256
#define NCLS   40
#define MNODES 16   // nodes per MLP block

static inline size_t align256(size_t x) { return (x + 255) & ~(size_t)255; }

// ---- degree count ----
__global__ void count_deg_kernel(const int* __restrict__ dst, int* __restrict__ deg, int E) {
    int e = blockIdx.x * blockDim.x + threadIdx.x;
    if (e < E) atomicAdd(&deg[dst[e]], 1);
}

// ---- single-block exclusive scan over deg -> offsets, cursor; also norm ----
__global__ void scan_kernel(const int* __restrict__ deg, int* __restrict__ offs,
                            int* __restrict__ cursor, float* __restrict__ norm, int N) {
    __shared__ int tile[1024];
    __shared__ int carry_s;
    if (threadIdx.x == 0) carry_s = 0;
    __syncthreads();
    for (int base = 0; base < N; base += 1024) {
        int i = base + threadIdx.x;
        int v = (i < N) ? deg[i] : 0;
        tile[threadIdx.x] = v;
        __syncthreads();
        for (int off = 1; off < 1024; off <<= 1) {
            int t = (threadIdx.x >= off) ? tile[threadIdx.x - off] : 0;
            __syncthreads();
            tile[threadIdx.x] += t;
            __syncthreads();
        }
        int excl = tile[threadIdx.x] - v;   // exclusive within tile
        if (i < N) {
            int o = carry_s + excl;
            offs[i] = o; cursor[i] = o;
            norm[i] = rsqrtf((float)(v > 0 ? v : 1));
        }
        __syncthreads();
        if (threadIdx.x == 1023) carry_s += tile[1023];
        __syncthreads();
    }
    if (threadIdx.x == 0) offs[N] = carry_s;
}

// ---- scatter edges into CSR-by-dst ----
__global__ void scatter_kernel(const int* __restrict__ src, const int* __restrict__ dst,
                               int* __restrict__ cursor, int* __restrict__ csr_src, int E) {
    int e = blockIdx.x * blockDim.x + threadIdx.x;
    if (e < E) {
        int p = atomicAdd(&cursor[dst[e]], 1);
        csr_src[p] = src[e];
    }
}

// ---- one propagation step: xout[v] = sum_{e: dst=v} xin[src]*norm[src]*norm[v];
//      y = (first ? feat + xout : y + xout) ----
__global__ __launch_bounds__(128) void prop_kernel(
        const float* __restrict__ xin, float* __restrict__ xout,
        float* __restrict__ y, const float* __restrict__ feat,
        const int* __restrict__ offs, const int* __restrict__ csr_src,
        const float* __restrict__ norm, int first) {
    int v = blockIdx.x;
    int f = threadIdx.x;
    int start = offs[v], end = offs[v + 1];
    float nv = norm[v];
    __shared__ int   sIdx[128];
    __shared__ float sW[128];
    float acc = 0.f;
    for (int k = start; k < end; k += 128) {
        int cnt = min(128, end - k);
        if (f < cnt) {
            int s = csr_src[k + f];
            sIdx[f] = s;
            sW[f]   = norm[s] * nv;
        }
        __syncthreads();
        for (int j = 0; j < cnt; ++j)
            acc += xin[(long)sIdx[j] * IN_DIM + f] * sW[j];
        __syncthreads();
    }
    long o = (long)v * IN_DIM + f;
    xout[o] = acc;
    if (first) y[o] = feat[o] + acc;
    else       y[o] += acc;
}

// ---- fused MLP + log_softmax: out = log_softmax(relu((y/4)@W1+b1)@W2+b2) ----
__global__ __launch_bounds__(256) void mlp_kernel(
        const float* __restrict__ y,
        const float* __restrict__ W1, const float* __restrict__ b1,
        const float* __restrict__ W2, const float* __restrict__ b2,
        float* __restrict__ out, int N) {
    __shared__ float sFeat[MNODES][IN_DIM];
    __shared__ float sH[MNODES][HID];
    __shared__ float sLog[MNODES][NCLS];
    __shared__ float sM[MNODES], sS[MNODES];
    int n0 = blockIdx.x * MNODES;
    int t  = threadIdx.x;

    // stage feat tile (already includes /4 scaling)
    for (int idx = t; idx < MNODES * IN_DIM; idx += 256) {
        int n = idx >> 7, i = idx & (IN_DIM - 1);
        int gv = n0 + n;
        sFeat[n][i] = (gv < N) ? y[(long)gv * IN_DIM + i] * 0.25f : 0.f;
    }
    __syncthreads();

    // hidden layer: thread t owns hidden column t for all MNODES nodes
    float acc[MNODES];
#pragma unroll
    for (int n = 0; n < MNODES; ++n) acc[n] = 0.f;
    for (int i = 0; i < IN_DIM; ++i) {
        float w = W1[i * HID + t];
#pragma unroll
        for (int n = 0; n < MNODES; ++n) acc[n] += sFeat[n][i] * w;
    }
    float bb = b1[t];
#pragma unroll
    for (int n = 0; n < MNODES; ++n) sH[n][t] = fmaxf(acc[n] + bb, 0.f);
    __syncthreads();

    // logits: MNODES*NCLS outputs spread over threads
    for (int o = t; o < MNODES * NCLS; o += 256) {
        int n = o / NCLS, c = o % NCLS;
        float a = b2[c];
        for (int i = 0; i < HID; ++i) a += sH[n][i] * W2[i * NCLS + c];
        sLog[n][c] = a;
    }
    __syncthreads();

    // per-node log-softmax stats
    if (t < MNODES) {
        float m = -1e30f;
        for (int c = 0; c < NCLS; ++c) m = fmaxf(m, sLog[t][c]);
        float s = 0.f;
        for (int c = 0; c < NCLS; ++c) s += expf(sLog[t][c] - m);
        sM[t] = m; sS[t] = logf(s);
    }
    __syncthreads();

    for (int o = t; o < MNODES * NCLS; o += 256) {
        int n = o / NCLS, c = o % NCLS;
        int gv = n0 + n;
        if (gv < N) out[(long)gv * NCLS + c] = sLog[n][c] - sM[n] - sS[n];
    }
}

extern "C" void kernel_launch(void* const* d_in, const int* in_sizes, int n_in,
                              void* d_out, int out_size, void* d_ws, size_t ws_size,
                              hipStream_t stream) {
    const float* feat = (const float*)d_in[0];
    const int*   src  = (const int*)d_in[1];
    const int*   dst  = (const int*)d_in[2];
    const float* W1   = (const float*)d_in[3];
    const float* b1   = (const float*)d_in[4];
    const float* W2   = (const float*)d_in[5];
    const float* b2   = (const float*)d_in[6];
    float* out = (float*)d_out;

    int N = in_sizes[0] / IN_DIM;
    int E = in_sizes[1];

    // workspace layout
    char* ws = (char*)d_ws;
    size_t off = 0;
    int*   deg     = (int*)(ws + off);  off += align256((size_t)N * 4);
    float* norm    = (float*)(ws + off); off += align256((size_t)N * 4);
    int*   offs    = (int*)(ws + off);  off += align256((size_t)(N + 1) * 4);
    int*   cursor  = (int*)(ws + off);  off += align256((size_t)N * 4);
    int*   csr_src = (int*)(ws + off);  off += align256((size_t)E * 4);
    float* xA      = (float*)(ws + off); off += align256((size_t)N * IN_DIM * 4);
    float* xB      = (float*)(ws + off); off += align256((size_t)N * IN_DIM * 4);
    float* ybuf    = (float*)(ws + off); off += align256((size_t)N * IN_DIM * 4);
    (void)ws_size;

    hipMemsetAsync(deg, 0, (size_t)N * 4, stream);

    int eb = (E + 255) / 256;
    count_deg_kernel<<<eb, 256, 0, stream>>>(dst, deg, E);
    scan_kernel<<<1, 1024, 0, stream>>>(deg, offs, cursor, norm, N);
    scatter_kernel<<<eb, 256, 0, stream>>>(src, dst, cursor, csr_src, E);

    prop_kernel<<<N, 128, 0, stream>>>(feat, xA, ybuf, feat, offs, csr_src, norm, 1);
    prop_kernel<<<N, 128, 0, stream>>>(xA,   xB, ybuf, feat, offs, csr_src, norm, 0);
    prop_kernel<<<N, 128, 0, stream>>>(xB,   xA, ybuf, feat, offs, csr_src, norm, 0);

    mlp_kernel<<<(N + MNODES - 1) / MNODES, 256, 0, stream>>>(ybuf, W1, b1, W2, b2, out, N);
}

// Round 2
// 362.121 us; speedup vs baseline: 1.6531x; 1.6531x over previous
//
#include <hip/hip_runtime.h>

#define IN_DIM 128
#define HID    256
#define NCLS   40

static inline size_t align256(size_t x) { return (x + 255) & ~(size_t)255; }

__device__ inline unsigned pack_bf16x2(float x, float y) {
    unsigned xb = __float_as_uint(x), yb = __float_as_uint(y);
    unsigned lo = (xb + 0x7fffu + ((xb >> 16) & 1u)) >> 16;
    unsigned hi = (yb + 0x7fffu + ((yb >> 16) & 1u)) >> 16;
    return lo | (hi << 16);
}
__device__ inline unsigned short f2bf(float x) {
    unsigned b = __float_as_uint(x);
    return (unsigned short)((b + 0x7fffu + ((b >> 16) & 1u)) >> 16);
}

// ---- degree count ----
__global__ void count_deg_kernel(const int* __restrict__ dst, int* __restrict__ deg, int E) {
    int e = blockIdx.x * blockDim.x + threadIdx.x;
    if (e < E) atomicAdd(&deg[dst[e]], 1);
}

// ---- single-block scan (shuffle-based) -> offs, cursor, norm ----
__global__ __launch_bounds__(1024) void scan_kernel(const int* __restrict__ deg, int* __restrict__ offs,
                            int* __restrict__ cursor, float* __restrict__ norm, int N) {
    __shared__ int waveSums[16];
    __shared__ int carry_s;
    int t = threadIdx.x, wave = t >> 6, lane = t & 63;
    if (t == 0) carry_s = 0;
    __syncthreads();
    for (int base = 0; base < N; base += 1024) {
        int i = base + t;
        int v = (i < N) ? deg[i] : 0;
        int s = v;
        for (int off = 1; off < 64; off <<= 1) {
            int u = __shfl_up(s, off, 64);
            if (lane >= off) s += u;
        }
        if (lane == 63) waveSums[wave] = s;
        __syncthreads();
        if (wave == 0 && lane < 16) {
            int ws = waveSums[lane];
            int ss = ws;
            for (int off = 1; off < 16; off <<= 1) {
                int u = __shfl_up(ss, off, 64);
                if (lane >= off) ss += u;
            }
            waveSums[lane] = ss - ws;   // exclusive over waves
        }
        __syncthreads();
        int excl = carry_s + waveSums[wave] + (s - v);
        if (i < N) {
            offs[i] = excl; cursor[i] = excl;
            norm[i] = rsqrtf((float)(v > 0 ? v : 1));
        }
        __syncthreads();
        if (t == 1023) carry_s = excl + v;
        __syncthreads();
    }
    if (t == 0) offs[N] = carry_s;
}

// ---- scatter edges into CSR-by-dst with precomputed weight ----
__global__ void scatter_kernel(const int* __restrict__ src, const int* __restrict__ dst,
                               int* __restrict__ cursor, int2* __restrict__ csr,
                               const float* __restrict__ norm, int E) {
    int e = blockIdx.x * blockDim.x + threadIdx.x;
    if (e < E) {
        int s = src[e], d = dst[e];
        int p = atomicAdd(&cursor[d], 1);
        csr[p] = make_int2(s, __float_as_int(norm[s] * norm[d]));
    }
}

// ---- fp32 -> bf16x2 cast ----
__global__ void cast_kernel(const float* __restrict__ feat, unsigned* __restrict__ xb, int n) {
    int i = blockIdx.x * blockDim.x + threadIdx.x;
    if (i < n) {
        float2 f = *(const float2*)(feat + (size_t)i * 2);
        xb[i] = pack_bf16x2(f.x, f.y);
    }
}

// ---- one propagation step over bf16 features; y accumulated fp32 ----
__global__ __launch_bounds__(64) void prop_kernel(
        const unsigned* __restrict__ xin, unsigned* __restrict__ xout,
        float* __restrict__ y, const float* __restrict__ feat,
        const int* __restrict__ offs, const int2* __restrict__ csr, int first) {
    int v = blockIdx.x, t = threadIdx.x;
    int start = offs[v], end = offs[v + 1];
    __shared__ int2 sIW[64];
    float a0 = 0.f, a1 = 0.f;
    for (int k = start; k < end; k += 64) {
        int cnt = min(64, end - k);
        if (t < cnt) sIW[t] = csr[k + t];
        __syncthreads();
        int j = 0;
        for (; j + 8 <= cnt; j += 8) {
            unsigned d[8]; float w[8];
#pragma unroll
            for (int u = 0; u < 8; ++u) {
                int2 e = sIW[j + u];
                w[u] = __int_as_float(e.y);
                d[u] = xin[e.x * 64 + t];
            }
#pragma unroll
            for (int u = 0; u < 8; ++u) {
                a0 += __uint_as_float(d[u] << 16) * w[u];
                a1 += __uint_as_float(d[u] & 0xffff0000u) * w[u];
            }
        }
        for (; j < cnt; ++j) {
            int2 e = sIW[j];
            float w = __int_as_float(e.y);
            unsigned d = xin[e.x * 64 + t];
            a0 += __uint_as_float(d << 16) * w;
            a1 += __uint_as_float(d & 0xffff0000u) * w;
        }
        __syncthreads();
    }
    xout[v * 64 + t] = pack_bf16x2(a0, a1);
    int yo = v * 128 + 2 * t;
    if (first) {
        float2 f = *(const float2*)(feat + yo);
        y[yo] = f.x + a0; y[yo + 1] = f.y + a1;
    } else {
        y[yo] += a0; y[yo + 1] += a1;
    }
}

// ---- convert/transposed weights to bf16 (once per launch) ----
__global__ void conv_weights_kernel(const float* __restrict__ W1, const float* __restrict__ W2,
                                    unsigned short* __restrict__ W1T, unsigned short* __restrict__ W2T) {
    int i = blockIdx.x * blockDim.x + threadIdx.x;
    if (i < 256 * 128) {                       // W1T[n][k] = W1[k][n]
        int n = i >> 7, k = i & 127;
        W1T[i] = f2bf(W1[k * 256 + n]);
    }
    int j = i - 256 * 128;
    if (j >= 0 && j < 48 * 256) {              // W2T[c][k] = W2[k][c], pad c to 48
        int c = j >> 8, k = j & 255;
        W2T[j] = (c < 40) ? f2bf(W2[k * 40 + c]) : (unsigned short)0;
    }
}

// ---- fused MFMA MLP + log_softmax ----
typedef __attribute__((ext_vector_type(8))) short bf16x8;
typedef __attribute__((ext_vector_type(4))) float f32x4;

#define SA_STRIDE 136   // 128 + 8 bf16 pad (row = 17 * 16B)
#define SH_STRIDE 264   // 256 + 8 bf16 pad (row = 33 * 16B)

__global__ __launch_bounds__(256) void mlp_kernel(
        const float* __restrict__ y,
        const unsigned short* __restrict__ W1T, const float* __restrict__ b1,
        const unsigned short* __restrict__ W2T, const float* __restrict__ b2,
        float* __restrict__ out, int N) {
    __shared__ unsigned short sA[64][SA_STRIDE];
    __shared__ unsigned short sH[64][SH_STRIDE];
    int t = threadIdx.x, wave = t >> 6, lane = t & 63;
    int n0 = blockIdx.x * 64;
    int l15 = lane & 15, lq = lane >> 4;

    // stage A tile: 64 nodes x 128 k, y*0.25 -> bf16
    for (int idx = t; idx < 64 * 64; idx += 256) {
        int n = idx >> 6, kp = idx & 63;
        int gv = n0 + n;
        float2 f = make_float2(0.f, 0.f);
        if (gv < N) f = *(const float2*)(y + (size_t)gv * 128 + kp * 2);
        *(unsigned*)&sA[n][kp * 2] = pack_bf16x2(f.x * 0.25f, f.y * 0.25f);
    }
    __syncthreads();

    // matmul1: this wave owns hid columns [wave*64, wave*64+64)
    f32x4 acc[4][4];
#pragma unroll
    for (int mt = 0; mt < 4; ++mt)
#pragma unroll
        for (int ht = 0; ht < 4; ++ht) acc[mt][ht] = (f32x4){0.f, 0.f, 0.f, 0.f};

#pragma unroll
    for (int s = 0; s < 4; ++s) {
        bf16x8 bfr[4];
#pragma unroll
        for (int ht = 0; ht < 4; ++ht) {
            const unsigned short* p = W1T + ((wave * 64 + ht * 16 + l15) * 128 + s * 32 + lq * 8);
            bfr[ht] = *(const bf16x8*)p;
        }
#pragma unroll
        for (int mt = 0; mt < 4; ++mt) {
            bf16x8 afr = *(const bf16x8*)&sA[mt * 16 + l15][s * 32 + lq * 8];
#pragma unroll
            for (int ht = 0; ht < 4; ++ht)
                acc[mt][ht] = __builtin_amdgcn_mfma_f32_16x16x32_bf16(afr, bfr[ht], acc[mt][ht], 0, 0, 0);
        }
    }

    // bias + relu -> sH (bf16)
#pragma unroll
    for (int ht = 0; ht < 4; ++ht) {
        int hid = wave * 64 + ht * 16 + l15;
        float bb = b1[hid];
#pragma unroll
        for (int mt = 0; mt < 4; ++mt) {
#pragma unroll
            for (int r = 0; r < 4; ++r) {
                int node = mt * 16 + lq * 4 + r;
                float h = fmaxf(acc[mt][ht][r] + bb, 0.f);
                sH[node][hid] = f2bf(h);
            }
        }
    }
    __syncthreads();

    // matmul2: wave owns node tile [wave*16, +16), 3 class tiles (48 padded), K=256
    f32x4 acc2[3];
#pragma unroll
    for (int ct = 0; ct < 3; ++ct) acc2[ct] = (f32x4){0.f, 0.f, 0.f, 0.f};
#pragma unroll
    for (int s = 0; s < 8; ++s) {
        bf16x8 afr = *(const bf16x8*)&sH[wave * 16 + l15][s * 32 + lq * 8];
#pragma unroll
        for (int ct = 0; ct < 3; ++ct) {
            const unsigned short* p = W2T + ((ct * 16 + l15) * 256 + s * 32 + lq * 8);
            bf16x8 bfr = *(const bf16x8*)p;
            acc2[ct] = __builtin_amdgcn_mfma_f32_16x16x32_bf16(afr, bfr, acc2[ct], 0, 0, 0);
        }
    }

    // + b2, log_softmax over 40 classes, write out
    float lg[3][4];
#pragma unroll
    for (int ct = 0; ct < 3; ++ct) {
        int c = ct * 16 + l15;
        float bb = (c < NCLS) ? b2[c] : 0.f;
#pragma unroll
        for (int r = 0; r < 4; ++r) lg[ct][r] = acc2[ct][r] + bb;
    }
#pragma unroll
    for (int r = 0; r < 4; ++r) {
        float m = fmaxf(lg[0][r], lg[1][r]);
        if (l15 < 8) m = fmaxf(m, lg[2][r]);
        for (int off = 1; off < 16; off <<= 1) m = fmaxf(m, __shfl_xor(m, off, 64));
        float ssum = __expf(lg[0][r] - m) + __expf(lg[1][r] - m) +
                     ((l15 < 8) ? __expf(lg[2][r] - m) : 0.f);
        for (int off = 1; off < 16; off <<= 1) ssum += __shfl_xor(ssum, off, 64);
        float ls = m + __logf(ssum);
        int node = n0 + wave * 16 + lq * 4 + r;
        if (node < N) {
#pragma unroll
            for (int ct = 0; ct < 3; ++ct) {
                int c = ct * 16 + l15;
                if (c < NCLS) out[(size_t)node * NCLS + c] = lg[ct][r] - ls;
            }
        }
    }
}

extern "C" void kernel_launch(void* const* d_in, const int* in_sizes, int n_in,
                              void* d_out, int out_size, void* d_ws, size_t ws_size,
                              hipStream_t stream) {
    const float* feat = (const float*)d_in[0];
    const int*   src  = (const int*)d_in[1];
    const int*   dst  = (const int*)d_in[2];
    const float* W1   = (const float*)d_in[3];
    const float* b1   = (const float*)d_in[4];
    const float* W2   = (const float*)d_in[5];
    const float* b2   = (const float*)d_in[6];
    float* out = (float*)d_out;

    int N = in_sizes[0] / IN_DIM;
    int E = in_sizes[1];

    char* ws = (char*)d_ws;
    size_t off = 0;
    int*   deg    = (int*)(ws + off);   off += align256((size_t)N * 4);
    float* norm   = (float*)(ws + off); off += align256((size_t)N * 4);
    int*   offs   = (int*)(ws + off);   off += align256((size_t)(N + 1) * 4);
    int*   cursor = (int*)(ws + off);   off += align256((size_t)N * 4);
    int2*  csr    = (int2*)(ws + off);  off += align256((size_t)E * 8);
    unsigned* xb0 = (unsigned*)(ws + off); off += align256((size_t)N * 64 * 4);
    unsigned* xb1 = (unsigned*)(ws + off); off += align256((size_t)N * 64 * 4);
    float* ybuf   = (float*)(ws + off); off += align256((size_t)N * IN_DIM * 4);
    unsigned short* W1T = (unsigned short*)(ws + off); off += align256((size_t)256 * 128 * 2);
    unsigned short* W2T = (unsigned short*)(ws + off); off += align256((size_t)48 * 256 * 2);
    (void)ws_size;

    hipMemsetAsync(deg, 0, (size_t)N * 4, stream);

    int eb = (E + 255) / 256;
    count_deg_kernel<<<eb, 256, 0, stream>>>(dst, deg, E);
    scan_kernel<<<1, 1024, 0, stream>>>(deg, offs, cursor, norm, N);
    scatter_kernel<<<eb, 256, 0, stream>>>(src, dst, cursor, csr, norm, E);
    conv_weights_kernel<<<(256 * 128 + 48 * 256 + 255) / 256, 256, 0, stream>>>(W1, W2, W1T, W2T);
    cast_kernel<<<(N * 64 + 255) / 256, 256, 0, stream>>>(feat, xb0, N * 64);

    prop_kernel<<<N, 64, 0, stream>>>(xb0, xb1, ybuf, feat, offs, csr, 1);
    prop_kernel<<<N, 64, 0, stream>>>(xb1, xb0, ybuf, feat, offs, csr, 0);
    prop_kernel<<<N, 64, 0, stream>>>(xb0, xb1, ybuf, feat, offs, csr, 0);

    mlp_kernel<<<(N + 63) / 64, 256, 0, stream>>>(ybuf, W1T, b1, W2T, b2, out, N);
}

// Round 3
// 308.484 us; speedup vs baseline: 1.9405x; 1.1739x over previous
//
#include <hip/hip_runtime.h>

#define IN_DIM 128
#define HID    256
#define NCLS   40

static inline size_t align256(size_t x) { return (x + 255) & ~(size_t)255; }

__device__ inline unsigned pack_bf16x2(float x, float y) {
    unsigned xb = __float_as_uint(x), yb = __float_as_uint(y);
    unsigned lo = (xb + 0x7fffu + ((xb >> 16) & 1u)) >> 16;
    unsigned hi = (yb + 0x7fffu + ((yb >> 16) & 1u)) >> 16;
    return lo | (hi << 16);
}
__device__ inline unsigned short f2bf(float x) {
    unsigned b = __float_as_uint(x);
    return (unsigned short)((b + 0x7fffu + ((b >> 16) & 1u)) >> 16);
}
__device__ inline float lo16(unsigned u) { return __uint_as_float(u << 16); }
__device__ inline float hi16(unsigned u) { return __uint_as_float(u & 0xffff0000u); }

// ---- degree count ----
__global__ void count_deg_kernel(const int* __restrict__ dst, int* __restrict__ deg, int E) {
    int e = blockIdx.x * blockDim.x + threadIdx.x;
    if (e < E) atomicAdd(&deg[dst[e]], 1);
}

// ---- hierarchical scan: pass 1, per-block (1024-elem) sums ----
__global__ __launch_bounds__(1024) void scan_partial_kernel(
        const int* __restrict__ deg, int* __restrict__ bsum, int N) {
    int i = blockIdx.x * 1024 + threadIdx.x;
    int v = (i < N) ? deg[i] : 0;
    int lane = threadIdx.x & 63, wave = threadIdx.x >> 6;
    for (int off = 32; off; off >>= 1) v += __shfl_down(v, off, 64);
    __shared__ int ws[16];
    if (lane == 0) ws[wave] = v;
    __syncthreads();
    if (threadIdx.x < 16) {
        int s = ws[threadIdx.x];
        for (int off = 8; off; off >>= 1) s += __shfl_down(s, off, 64);
        if (threadIdx.x == 0) bsum[blockIdx.x] = s;
    }
}

// ---- pass 2: scan block sums (one block, nb <= 1024), writes offs[N]=total ----
__global__ __launch_bounds__(1024) void scan_bsum_kernel(
        int* __restrict__ bsum, int* __restrict__ offs, int nb, int N) {
    int t = threadIdx.x;
    int v = (t < nb) ? bsum[t] : 0;
    int lane = t & 63, wave = t >> 6;
    int s = v;
    for (int off = 1; off < 64; off <<= 1) {
        int u = __shfl_up(s, off, 64);
        if (lane >= off) s += u;
    }
    __shared__ int ws[16];
    if (lane == 63) ws[wave] = s;
    __syncthreads();
    if (t < 16) {
        int x = ws[t], ss = x;
        for (int off = 1; off < 16; off <<= 1) {
            int u = __shfl_up(ss, off, 64);
            if (t >= off) ss += u;
        }
        ws[t] = ss - x;
    }
    __syncthreads();
    int incl = ws[wave] + s;
    if (t < nb) bsum[t] = incl - v;        // exclusive base per block
    if (t == nb - 1) offs[N] = incl;       // grand total
}

// ---- pass 3: local scan + block base -> offs/cursor/norm ----
__global__ __launch_bounds__(1024) void scan_final_kernel(
        const int* __restrict__ deg, const int* __restrict__ bbase,
        int* __restrict__ offs, int* __restrict__ cursor, float* __restrict__ norm, int N) {
    int i = blockIdx.x * 1024 + threadIdx.x;
    int v = (i < N) ? deg[i] : 0;
    int lane = threadIdx.x & 63, wave = threadIdx.x >> 6;
    int s = v;
    for (int off = 1; off < 64; off <<= 1) {
        int u = __shfl_up(s, off, 64);
        if (lane >= off) s += u;
    }
    __shared__ int ws[16];
    if (lane == 63) ws[wave] = s;
    __syncthreads();
    if (threadIdx.x < 16) {
        int x = ws[threadIdx.x], ss = x;
        for (int off = 1; off < 16; off <<= 1) {
            int u = __shfl_up(ss, off, 64);
            if (threadIdx.x >= off) ss += u;
        }
        ws[threadIdx.x] = ss - x;
    }
    __syncthreads();
    if (i < N) {
        int excl = bbase[blockIdx.x] + ws[wave] + (s - v);
        offs[i] = excl; cursor[i] = excl;
        norm[i] = rsqrtf((float)(v > 0 ? v : 1));
    }
}

// ---- scatter edges into CSR-by-dst with precomputed weight ----
__global__ void scatter_kernel(const int* __restrict__ src, const int* __restrict__ dst,
                               int* __restrict__ cursor, int2* __restrict__ csr,
                               const float* __restrict__ norm, int E) {
    int e = blockIdx.x * blockDim.x + threadIdx.x;
    if (e < E) {
        int s = src[e], d = dst[e];
        int p = atomicAdd(&cursor[d], 1);
        csr[p] = make_int2(s, __float_as_int(norm[s] * norm[d]));
    }
}

// ---- fp32 -> bf16x2 cast ----
__global__ void cast_kernel(const float* __restrict__ feat, unsigned* __restrict__ xb, int n) {
    int i = blockIdx.x * blockDim.x + threadIdx.x;
    if (i < n) {
        float2 f = *(const float2*)(feat + (size_t)i * 2);
        xb[i] = pack_bf16x2(f.x, f.y);
    }
}

// ---- one propagation step: half-wave per edge, dwordx2 gathers ----
__global__ __launch_bounds__(64) void prop_kernel(
        const unsigned* __restrict__ xin, unsigned* __restrict__ xout,
        float* __restrict__ y, const float* __restrict__ feat,
        const int* __restrict__ offs, const int2* __restrict__ csr, int first) {
    int v = blockIdx.x, t = threadIdx.x;
    int half = t >> 5, hl = t & 31;
    int start = offs[v], end = offs[v + 1];
    __shared__ int2 sIW[64];
    float a0 = 0.f, a1 = 0.f, a2 = 0.f, a3 = 0.f;
    for (int k = start; k < end; k += 64) {
        int cnt = min(64, end - k);
        if (t < cnt) sIW[t] = csr[k + t];
        __syncthreads();
        int j = 0;
        for (; j + 8 <= cnt; j += 8) {   // 4 edge-pairs in flight
            uint2 d[4]; float w[4];
#pragma unroll
            for (int u = 0; u < 4; ++u) {
                int2 e = sIW[j + 2 * u + half];
                w[u] = __int_as_float(e.y);
                d[u] = *(const uint2*)(xin + (size_t)e.x * 64 + hl * 2);
            }
#pragma unroll
            for (int u = 0; u < 4; ++u) {
                a0 += lo16(d[u].x) * w[u];
                a1 += hi16(d[u].x) * w[u];
                a2 += lo16(d[u].y) * w[u];
                a3 += hi16(d[u].y) * w[u];
            }
        }
        for (; j < cnt; j += 2) {
            int idx = j + half;
            float w = 0.f; uint2 d = make_uint2(0u, 0u);
            if (idx < cnt) {
                int2 e = sIW[idx];
                w = __int_as_float(e.y);
                d = *(const uint2*)(xin + (size_t)e.x * 64 + hl * 2);
            }
            a0 += lo16(d.x) * w; a1 += hi16(d.x) * w;
            a2 += lo16(d.y) * w; a3 += hi16(d.y) * w;
        }
        __syncthreads();
    }
    // combine the two halves
    a0 += __shfl_xor(a0, 32, 64);
    a1 += __shfl_xor(a1, 32, 64);
    a2 += __shfl_xor(a2, 32, 64);
    a3 += __shfl_xor(a3, 32, 64);
    if (half == 0) {
        uint2 o;
        o.x = pack_bf16x2(a0, a1);
        o.y = pack_bf16x2(a2, a3);
        *(uint2*)(xout + (size_t)v * 64 + hl * 2) = o;
        size_t yo = (size_t)v * 128 + hl * 4;
        if (first) {
            float4 f = *(const float4*)(feat + yo);
            *(float4*)(y + yo) = make_float4(f.x + a0, f.y + a1, f.z + a2, f.w + a3);
        } else {
            float4 f = *(const float4*)(y + yo);
            *(float4*)(y + yo) = make_float4(f.x + a0, f.y + a1, f.z + a2, f.w + a3);
        }
    }
}

// ---- convert/transposed weights to bf16 (once per launch) ----
__global__ void conv_weights_kernel(const float* __restrict__ W1, const float* __restrict__ W2,
                                    unsigned short* __restrict__ W1T, unsigned short* __restrict__ W2T) {
    int i = blockIdx.x * blockDim.x + threadIdx.x;
    if (i < 256 * 128) {                       // W1T[n][k] = W1[k][n]
        int n = i >> 7, k = i & 127;
        W1T[i] = f2bf(W1[k * 256 + n]);
    }
    int j = i - 256 * 128;
    if (j >= 0 && j < 48 * 256) {              // W2T[c][k] = W2[k][c], pad c to 48
        int c = j >> 8, k = j & 255;
        W2T[j] = (c < 40) ? f2bf(W2[k * 40 + c]) : (unsigned short)0;
    }
}

// ---- fused MFMA MLP + log_softmax ----
typedef __attribute__((ext_vector_type(8))) short bf16x8;
typedef __attribute__((ext_vector_type(4))) float f32x4;

#define SA_STRIDE 136   // 128 + 8 bf16 pad
#define SH_STRIDE 264   // 256 + 8 bf16 pad

__global__ __launch_bounds__(256) void mlp_kernel(
        const float* __restrict__ y,
        const unsigned short* __restrict__ W1T, const float* __restrict__ b1,
        const unsigned short* __restrict__ W2T, const float* __restrict__ b2,
        float* __restrict__ out, int N) {
    __shared__ unsigned short sA[64][SA_STRIDE];
    __shared__ unsigned short sH[64][SH_STRIDE];
    int t = threadIdx.x, wave = t >> 6, lane = t & 63;
    int n0 = blockIdx.x * 64;
    int l15 = lane & 15, lq = lane >> 4;

    for (int idx = t; idx < 64 * 64; idx += 256) {
        int n = idx >> 6, kp = idx & 63;
        int gv = n0 + n;
        float2 f = make_float2(0.f, 0.f);
        if (gv < N) f = *(const float2*)(y + (size_t)gv * 128 + kp * 2);
        *(unsigned*)&sA[n][kp * 2] = pack_bf16x2(f.x * 0.25f, f.y * 0.25f);
    }
    __syncthreads();

    f32x4 acc[4][4];
#pragma unroll
    for (int mt = 0; mt < 4; ++mt)
#pragma unroll
        for (int ht = 0; ht < 4; ++ht) acc[mt][ht] = (f32x4){0.f, 0.f, 0.f, 0.f};

#pragma unroll
    for (int s = 0; s < 4; ++s) {
        bf16x8 bfr[4];
#pragma unroll
        for (int ht = 0; ht < 4; ++ht) {
            const unsigned short* p = W1T + ((wave * 64 + ht * 16 + l15) * 128 + s * 32 + lq * 8);
            bfr[ht] = *(const bf16x8*)p;
        }
#pragma unroll
        for (int mt = 0; mt < 4; ++mt) {
            bf16x8 afr = *(const bf16x8*)&sA[mt * 16 + l15][s * 32 + lq * 8];
#pragma unroll
            for (int ht = 0; ht < 4; ++ht)
                acc[mt][ht] = __builtin_amdgcn_mfma_f32_16x16x32_bf16(afr, bfr[ht], acc[mt][ht], 0, 0, 0);
        }
    }

#pragma unroll
    for (int ht = 0; ht < 4; ++ht) {
        int hid = wave * 64 + ht * 16 + l15;
        float bb = b1[hid];
#pragma unroll
        for (int mt = 0; mt < 4; ++mt) {
#pragma unroll
            for (int r = 0; r < 4; ++r) {
                int node = mt * 16 + lq * 4 + r;
                float h = fmaxf(acc[mt][ht][r] + bb, 0.f);
                sH[node][hid] = f2bf(h);
            }
        }
    }
    __syncthreads();

    f32x4 acc2[3];
#pragma unroll
    for (int ct = 0; ct < 3; ++ct) acc2[ct] = (f32x4){0.f, 0.f, 0.f, 0.f};
#pragma unroll
    for (int s = 0; s < 8; ++s) {
        bf16x8 afr = *(const bf16x8*)&sH[wave * 16 + l15][s * 32 + lq * 8];
#pragma unroll
        for (int ct = 0; ct < 3; ++ct) {
            const unsigned short* p = W2T + ((ct * 16 + l15) * 256 + s * 32 + lq * 8);
            bf16x8 bfr = *(const bf16x8*)p;
            acc2[ct] = __builtin_amdgcn_mfma_f32_16x16x32_bf16(afr, bfr, acc2[ct], 0, 0, 0);
        }
    }

    float lg[3][4];
#pragma unroll
    for (int ct = 0; ct < 3; ++ct) {
        int c = ct * 16 + l15;
        float bb = (c < NCLS) ? b2[c] : 0.f;
#pragma unroll
        for (int r = 0; r < 4; ++r) lg[ct][r] = acc2[ct][r] + bb;
    }
#pragma unroll
    for (int r = 0; r < 4; ++r) {
        float m = fmaxf(lg[0][r], lg[1][r]);
        if (l15 < 8) m = fmaxf(m, lg[2][r]);
        for (int off = 1; off < 16; off <<= 1) m = fmaxf(m, __shfl_xor(m, off, 64));
        float ssum = __expf(lg[0][r] - m) + __expf(lg[1][r] - m) +
                     ((l15 < 8) ? __expf(lg[2][r] - m) : 0.f);
        for (int off = 1; off < 16; off <<= 1) ssum += __shfl_xor(ssum, off, 64);
        float ls = m + __logf(ssum);
        int node = n0 + wave * 16 + lq * 4 + r;
        if (node < N) {
#pragma unroll
            for (int ct = 0; ct < 3; ++ct) {
                int c = ct * 16 + l15;
                if (c < NCLS) out[(size_t)node * NCLS + c] = lg[ct][r] - ls;
            }
        }
    }
}

extern "C" void kernel_launch(void* const* d_in, const int* in_sizes, int n_in,
                              void* d_out, int out_size, void* d_ws, size_t ws_size,
                              hipStream_t stream) {
    const float* feat = (const float*)d_in[0];
    const int*   src  = (const int*)d_in[1];
    const int*   dst  = (const int*)d_in[2];
    const float* W1   = (const float*)d_in[3];
    const float* b1   = (const float*)d_in[4];
    const float* W2   = (const float*)d_in[5];
    const float* b2   = (const float*)d_in[6];
    float* out = (float*)d_out;

    int N = in_sizes[0] / IN_DIM;
    int E = in_sizes[1];
    int nb = (N + 1023) / 1024;

    char* ws = (char*)d_ws;
    size_t off = 0;
    int*   deg    = (int*)(ws + off);   off += align256((size_t)N * 4);
    float* norm   = (float*)(ws + off); off += align256((size_t)N * 4);
    int*   offs   = (int*)(ws + off);   off += align256((size_t)(N + 1) * 4);
    int*   cursor = (int*)(ws + off);   off += align256((size_t)N * 4);
    int*   bsum   = (int*)(ws + off);   off += align256((size_t)nb * 4);
    int2*  csr    = (int2*)(ws + off);  off += align256((size_t)E * 8);
    unsigned* xb0 = (unsigned*)(ws + off); off += align256((size_t)N * 64 * 4);
    unsigned* xb1 = (unsigned*)(ws + off); off += align256((size_t)N * 64 * 4);
    float* ybuf   = (float*)(ws + off); off += align256((size_t)N * IN_DIM * 4);
    unsigned short* W1T = (unsigned short*)(ws + off); off += align256((size_t)256 * 128 * 2);
    unsigned short* W2T = (unsigned short*)(ws + off); off += align256((size_t)48 * 256 * 2);
    (void)ws_size;

    hipMemsetAsync(deg, 0, (size_t)N * 4, stream);

    int eb = (E + 255) / 256;
    count_deg_kernel<<<eb, 256, 0, stream>>>(dst, deg, E);
    scan_partial_kernel<<<nb, 1024, 0, stream>>>(deg, bsum, N);
    scan_bsum_kernel<<<1, 1024, 0, stream>>>(bsum, offs, nb, N);
    scan_final_kernel<<<nb, 1024, 0, stream>>>(deg, bsum, offs, cursor, norm, N);
    scatter_kernel<<<eb, 256, 0, stream>>>(src, dst, cursor, csr, norm, E);
    conv_weights_kernel<<<(256 * 128 + 48 * 256 + 255) / 256, 256, 0, stream>>>(W1, W2, W1T, W2T);
    cast_kernel<<<(N * 64 + 255) / 256, 256, 0, stream>>>(feat, xb0, N * 64);

    prop_kernel<<<N, 64, 0, stream>>>(xb0, xb1, ybuf, feat, offs, csr, 1);
    prop_kernel<<<N, 64, 0, stream>>>(xb1, xb0, ybuf, feat, offs, csr, 0);
    prop_kernel<<<N, 64, 0, stream>>>(xb0, xb1, ybuf, feat, offs, csr, 0);

    mlp_kernel<<<(N + 63) / 64, 256, 0, stream>>>(ybuf, W1T, b1, W2T, b2, out, N);
}

// Round 4
// 266.525 us; speedup vs baseline: 2.2460x; 1.1574x over previous
//
#include <hip/hip_runtime.h>

#define IN_DIM 128
#define HID    256
#define NCLS   40
#define BSHIFT 8
#define BSZ    256     // nodes per bucket
#define MAXNB  256     // max buckets (N <= 65536)
#define CHUNK  4096    // edges per scatter block

static inline size_t align256(size_t x) { return (x + 255) & ~(size_t)255; }

__device__ inline unsigned pack_bf16x2(float x, float y) {
    unsigned xb = __float_as_uint(x), yb = __float_as_uint(y);
    unsigned lo = (xb + 0x7fffu + ((xb >> 16) & 1u)) >> 16;
    unsigned hi = (yb + 0x7fffu + ((yb >> 16) & 1u)) >> 16;
    return lo | (hi << 16);
}
__device__ inline unsigned short f2bf(float x) {
    unsigned b = __float_as_uint(x);
    return (unsigned short)((b + 0x7fffu + ((b >> 16) & 1u)) >> 16);
}
__device__ inline float lo16(unsigned u) { return __uint_as_float(u << 16); }
__device__ inline float hi16(unsigned u) { return __uint_as_float(u & 0xffff0000u); }

// 256-thread inclusive->exclusive scan helper pattern used inline below.

// ---- K1: bucket histogram ----
__global__ __launch_bounds__(256) void bucket_count_kernel(
        const int* __restrict__ dst, int* __restrict__ bucketCnt, int E, int NB) {
    __shared__ int hist[MAXNB];
    int t = threadIdx.x;
    hist[t] = 0;
    __syncthreads();
    int start = blockIdx.x * CHUNK;
    int cnt = min(CHUNK, E - start);
    for (int i = t; i < cnt; i += 256) atomicAdd(&hist[dst[start + i] >> BSHIFT], 1);
    __syncthreads();
    if (t < NB && hist[t]) atomicAdd(&bucketCnt[t], hist[t]);
}

// ---- K2: scan bucket totals -> bucketBase, bucketCursor; offs[N]=E ----
__global__ __launch_bounds__(256) void bucket_scan_kernel(
        const int* __restrict__ bucketCnt, int* __restrict__ bucketBase,
        int* __restrict__ bucketCursor, int* __restrict__ offs, int NB, int N) {
    int t = threadIdx.x, lane = t & 63, wave = t >> 6;
    int v = (t < NB) ? bucketCnt[t] : 0;
    int s = v;
    for (int off = 1; off < 64; off <<= 1) {
        int u = __shfl_up(s, off, 64);
        if (lane >= off) s += u;
    }
    __shared__ int wsum[4];
    if (lane == 63) wsum[wave] = s;
    __syncthreads();
    if (t == 0) {
        int c = 0;
        for (int i = 0; i < 4; ++i) { int x = wsum[i]; wsum[i] = c; c += x; }
    }
    __syncthreads();
    int incl = wsum[wave] + s;
    int excl = incl - v;
    if (t < NB) { bucketBase[t] = excl; bucketCursor[t] = excl; }
    if (t == NB - 1) { bucketBase[NB] = incl; offs[N] = incl; }
}

// ---- K3: bucket-ordered scatter of (src,dst) via LDS binning ----
__global__ __launch_bounds__(256) void bucket_scatter_kernel(
        const int* __restrict__ src, const int* __restrict__ dst,
        int* __restrict__ bucketCursor, int2* __restrict__ ebuf, int E) {
    __shared__ int hist[MAXNB], lofs[MAXNB], lcur[MAXNB], gbase[MAXNB];
    __shared__ int2 bin[CHUNK];
    int t = threadIdx.x, lane = t & 63, wave = t >> 6;
    int start = blockIdx.x * CHUNK;
    int cnt = min(CHUNK, E - start);
    hist[t] = 0;
    __syncthreads();
    for (int i = t; i < cnt; i += 256) atomicAdd(&hist[dst[start + i] >> BSHIFT], 1);
    __syncthreads();
    int v = hist[t];
    int s = v;
    for (int off = 1; off < 64; off <<= 1) {
        int u = __shfl_up(s, off, 64);
        if (lane >= off) s += u;
    }
    __shared__ int wsum[4];
    if (lane == 63) wsum[wave] = s;
    __syncthreads();
    if (t == 0) {
        int c = 0;
        for (int i = 0; i < 4; ++i) { int x = wsum[i]; wsum[i] = c; c += x; }
    }
    __syncthreads();
    int excl = wsum[wave] + s - v;
    lofs[t] = excl; lcur[t] = excl;
    if (v) gbase[t] = atomicAdd(&bucketCursor[t], v);
    __syncthreads();
    for (int i = t; i < cnt; i += 256) {
        int s0 = src[start + i], d0 = dst[start + i];
        int r = atomicAdd(&lcur[d0 >> BSHIFT], 1);
        bin[r] = make_int2(s0, d0);
    }
    __syncthreads();
    for (int i = t; i < cnt; i += 256) {
        int2 e = bin[i];
        int b = e.y >> BSHIFT;
        ebuf[gbase[b] + i - lofs[b]] = e;
    }
}

// ---- K4: per-bucket degrees -> offs, norm ----
__global__ __launch_bounds__(256) void build_norm_kernel(
        const int2* __restrict__ ebuf, const int* __restrict__ bucketBase,
        int* __restrict__ offs, float* __restrict__ norm, int N) {
    __shared__ int hist[BSZ];
    int b = blockIdx.x, t = threadIdx.x, lane = t & 63, wave = t >> 6;
    hist[t] = 0;
    __syncthreads();
    int segS = bucketBase[b], segE = bucketBase[b + 1];
    for (int i = segS + t; i < segE; i += 256) atomicAdd(&hist[ebuf[i].y & (BSZ - 1)], 1);
    __syncthreads();
    int v = hist[t];
    int s = v;
    for (int off = 1; off < 64; off <<= 1) {
        int u = __shfl_up(s, off, 64);
        if (lane >= off) s += u;
    }
    __shared__ int wsum[4];
    if (lane == 63) wsum[wave] = s;
    __syncthreads();
    if (t == 0) {
        int c = 0;
        for (int i = 0; i < 4; ++i) { int x = wsum[i]; wsum[i] = c; c += x; }
    }
    __syncthreads();
    int excl = wsum[wave] + s - v;
    int node = b * BSZ + t;
    if (node < N) {
        offs[node] = segS + excl;
        norm[node] = rsqrtf((float)(v > 0 ? v : 1));
    }
}

// ---- K5: per-bucket exact CSR placement with weights ----
__global__ __launch_bounds__(256) void build_csr_kernel(
        const int2* __restrict__ ebuf, const int* __restrict__ bucketBase,
        const int* __restrict__ offs, const float* __restrict__ norm,
        int2* __restrict__ csr, int N) {
    __shared__ int lcur[BSZ];
    __shared__ float snorm[BSZ];
    int b = blockIdx.x, t = threadIdx.x;
    int node = b * BSZ + t;
    lcur[t] = (node < N) ? offs[node] : 0;
    snorm[t] = (node < N) ? norm[node] : 0.f;
    __syncthreads();
    int segS = bucketBase[b], segE = bucketBase[b + 1];
    for (int i = segS + t; i < segE; i += 256) {
        int2 e = ebuf[i];
        int li = e.y & (BSZ - 1);
        float w = norm[e.x] * snorm[li];
        int p = atomicAdd(&lcur[li], 1);
        csr[p] = make_int2(e.x, __float_as_int(w));
    }
}

// ---- fp32 -> bf16x2 cast ----
__global__ void cast_kernel(const float* __restrict__ feat, unsigned* __restrict__ xb, int n) {
    int i = blockIdx.x * blockDim.x + threadIdx.x;
    if (i < n) {
        float2 f = *(const float2*)(feat + (size_t)i * 2);
        xb[i] = pack_bf16x2(f.x, f.y);
    }
}

// ---- one propagation step: half-wave per edge, dwordx2 gathers ----
__global__ __launch_bounds__(64) void prop_kernel(
        const unsigned* __restrict__ xin, unsigned* __restrict__ xout,
        float* __restrict__ y, const float* __restrict__ feat,
        const int* __restrict__ offs, const int2* __restrict__ csr, int first) {
    int v = blockIdx.x, t = threadIdx.x;
    int half = t >> 5, hl = t & 31;
    int start = offs[v], end = offs[v + 1];
    __shared__ int2 sIW[64];
    float a0 = 0.f, a1 = 0.f, a2 = 0.f, a3 = 0.f;
    for (int k = start; k < end; k += 64) {
        int cnt = min(64, end - k);
        if (t < cnt) sIW[t] = csr[k + t];
        __syncthreads();
        int j = 0;
        for (; j + 8 <= cnt; j += 8) {
            uint2 d[4]; float w[4];
#pragma unroll
            for (int u = 0; u < 4; ++u) {
                int2 e = sIW[j + 2 * u + half];
                w[u] = __int_as_float(e.y);
                d[u] = *(const uint2*)(xin + (size_t)e.x * 64 + hl * 2);
            }
#pragma unroll
            for (int u = 0; u < 4; ++u) {
                a0 += lo16(d[u].x) * w[u];
                a1 += hi16(d[u].x) * w[u];
                a2 += lo16(d[u].y) * w[u];
                a3 += hi16(d[u].y) * w[u];
            }
        }
        for (; j < cnt; j += 2) {
            int idx = j + half;
            float w = 0.f; uint2 d = make_uint2(0u, 0u);
            if (idx < cnt) {
                int2 e = sIW[idx];
                w = __int_as_float(e.y);
                d = *(const uint2*)(xin + (size_t)e.x * 64 + hl * 2);
            }
            a0 += lo16(d.x) * w; a1 += hi16(d.x) * w;
            a2 += lo16(d.y) * w; a3 += hi16(d.y) * w;
        }
        __syncthreads();
    }
    a0 += __shfl_xor(a0, 32, 64);
    a1 += __shfl_xor(a1, 32, 64);
    a2 += __shfl_xor(a2, 32, 64);
    a3 += __shfl_xor(a3, 32, 64);
    if (half == 0) {
        uint2 o;
        o.x = pack_bf16x2(a0, a1);
        o.y = pack_bf16x2(a2, a3);
        *(uint2*)(xout + (size_t)v * 64 + hl * 2) = o;
        size_t yo = (size_t)v * 128 + hl * 4;
        if (first) {
            float4 f = *(const float4*)(feat + yo);
            *(float4*)(y + yo) = make_float4(f.x + a0, f.y + a1, f.z + a2, f.w + a3);
        } else {
            float4 f = *(const float4*)(y + yo);
            *(float4*)(y + yo) = make_float4(f.x + a0, f.y + a1, f.z + a2, f.w + a3);
        }
    }
}

// ---- convert/transposed weights to bf16 ----
__global__ void conv_weights_kernel(const float* __restrict__ W1, const float* __restrict__ W2,
                                    unsigned short* __restrict__ W1T, unsigned short* __restrict__ W2T) {
    int i = blockIdx.x * blockDim.x + threadIdx.x;
    if (i < 256 * 128) {
        int n = i >> 7, k = i & 127;
        W1T[i] = f2bf(W1[k * 256 + n]);
    }
    int j = i - 256 * 128;
    if (j >= 0 && j < 48 * 256) {
        int c = j >> 8, k = j & 255;
        W2T[j] = (c < 40) ? f2bf(W2[k * 40 + c]) : (unsigned short)0;
    }
}

// ---- fused MFMA MLP + log_softmax ----
typedef __attribute__((ext_vector_type(8))) short bf16x8;
typedef __attribute__((ext_vector_type(4))) float f32x4;

#define SA_STRIDE 136
#define SH_STRIDE 264

__global__ __launch_bounds__(256) void mlp_kernel(
        const float* __restrict__ y,
        const unsigned short* __restrict__ W1T, const float* __restrict__ b1,
        const unsigned short* __restrict__ W2T, const float* __restrict__ b2,
        float* __restrict__ out, int N) {
    __shared__ unsigned short sA[64][SA_STRIDE];
    __shared__ unsigned short sH[64][SH_STRIDE];
    int t = threadIdx.x, wave = t >> 6, lane = t & 63;
    int n0 = blockIdx.x * 64;
    int l15 = lane & 15, lq = lane >> 4;

    for (int idx = t; idx < 64 * 64; idx += 256) {
        int n = idx >> 6, kp = idx & 63;
        int gv = n0 + n;
        float2 f = make_float2(0.f, 0.f);
        if (gv < N) f = *(const float2*)(y + (size_t)gv * 128 + kp * 2);
        *(unsigned*)&sA[n][kp * 2] = pack_bf16x2(f.x * 0.25f, f.y * 0.25f);
    }
    __syncthreads();

    f32x4 acc[4][4];
#pragma unroll
    for (int mt = 0; mt < 4; ++mt)
#pragma unroll
        for (int ht = 0; ht < 4; ++ht) acc[mt][ht] = (f32x4){0.f, 0.f, 0.f, 0.f};

#pragma unroll
    for (int s = 0; s < 4; ++s) {
        bf16x8 bfr[4];
#pragma unroll
        for (int ht = 0; ht < 4; ++ht) {
            const unsigned short* p = W1T + ((wave * 64 + ht * 16 + l15) * 128 + s * 32 + lq * 8);
            bfr[ht] = *(const bf16x8*)p;
        }
#pragma unroll
        for (int mt = 0; mt < 4; ++mt) {
            bf16x8 afr = *(const bf16x8*)&sA[mt * 16 + l15][s * 32 + lq * 8];
#pragma unroll
            for (int ht = 0; ht < 4; ++ht)
                acc[mt][ht] = __builtin_amdgcn_mfma_f32_16x16x32_bf16(afr, bfr[ht], acc[mt][ht], 0, 0, 0);
        }
    }

#pragma unroll
    for (int ht = 0; ht < 4; ++ht) {
        int hid = wave * 64 + ht * 16 + l15;
        float bb = b1[hid];
#pragma unroll
        for (int mt = 0; mt < 4; ++mt) {
#pragma unroll
            for (int r = 0; r < 4; ++r) {
                int node = mt * 16 + lq * 4 + r;
                float h = fmaxf(acc[mt][ht][r] + bb, 0.f);
                sH[node][hid] = f2bf(h);
            }
        }
    }
    __syncthreads();

    f32x4 acc2[3];
#pragma unroll
    for (int ct = 0; ct < 3; ++ct) acc2[ct] = (f32x4){0.f, 0.f, 0.f, 0.f};
#pragma unroll
    for (int s = 0; s < 8; ++s) {
        bf16x8 afr = *(const bf16x8*)&sH[wave * 16 + l15][s * 32 + lq * 8];
#pragma unroll
        for (int ct = 0; ct < 3; ++ct) {
            const unsigned short* p = W2T + ((ct * 16 + l15) * 256 + s * 32 + lq * 8);
            bf16x8 bfr = *(const bf16x8*)p;
            acc2[ct] = __builtin_amdgcn_mfma_f32_16x16x32_bf16(afr, bfr, acc2[ct], 0, 0, 0);
        }
    }

    float lg[3][4];
#pragma unroll
    for (int ct = 0; ct < 3; ++ct) {
        int c = ct * 16 + l15;
        float bb = (c < NCLS) ? b2[c] : 0.f;
#pragma unroll
        for (int r = 0; r < 4; ++r) lg[ct][r] = acc2[ct][r] + bb;
    }
#pragma unroll
    for (int r = 0; r < 4; ++r) {
        float m = fmaxf(lg[0][r], lg[1][r]);
        if (l15 < 8) m = fmaxf(m, lg[2][r]);
        for (int off = 1; off < 16; off <<= 1) m = fmaxf(m, __shfl_xor(m, off, 64));
        float ssum = __expf(lg[0][r] - m) + __expf(lg[1][r] - m) +
                     ((l15 < 8) ? __expf(lg[2][r] - m) : 0.f);
        for (int off = 1; off < 16; off <<= 1) ssum += __shfl_xor(ssum, off, 64);
        float ls = m + __logf(ssum);
        int node = n0 + wave * 16 + lq * 4 + r;
        if (node < N) {
#pragma unroll
            for (int ct = 0; ct < 3; ++ct) {
                int c = ct * 16 + l15;
                if (c < NCLS) out[(size_t)node * NCLS + c] = lg[ct][r] - ls;
            }
        }
    }
}

extern "C" void kernel_launch(void* const* d_in, const int* in_sizes, int n_in,
                              void* d_out, int out_size, void* d_ws, size_t ws_size,
                              hipStream_t stream) {
    const float* feat = (const float*)d_in[0];
    const int*   src  = (const int*)d_in[1];
    const int*   dst  = (const int*)d_in[2];
    const float* W1   = (const float*)d_in[3];
    const float* b1   = (const float*)d_in[4];
    const float* W2   = (const float*)d_in[5];
    const float* b2   = (const float*)d_in[6];
    float* out = (float*)d_out;

    int N = in_sizes[0] / IN_DIM;
    int E = in_sizes[1];
    int NB = (N + BSZ - 1) / BSZ;   // 196 for N=50000

    char* ws = (char*)d_ws;
    size_t off = 0;
    float* norm   = (float*)(ws + off); off += align256((size_t)N * 4);
    int*   offs   = (int*)(ws + off);   off += align256((size_t)(N + 1) * 4);
    int*   bBase  = (int*)(ws + off);   off += align256((size_t)(MAXNB + 1) * 4);
    int*   bCur   = (int*)(ws + off);   off += align256((size_t)MAXNB * 4);
    int*   bCnt   = (int*)(ws + off);   off += align256((size_t)MAXNB * 4);
    int2*  csr    = (int2*)(ws + off);  off += align256((size_t)E * 8);
    unsigned* xb0 = (unsigned*)(ws + off); off += align256((size_t)N * 64 * 4);
    unsigned* xb1 = (unsigned*)(ws + off); off += align256((size_t)N * 64 * 4);
    float* ybuf   = (float*)(ws + off); off += align256((size_t)N * IN_DIM * 4);
    unsigned short* W1T = (unsigned short*)(ws + off); off += align256((size_t)256 * 128 * 2);
    unsigned short* W2T = (unsigned short*)(ws + off); off += align256((size_t)48 * 256 * 2);
    (void)ws_size;
    int2* ebuf = (int2*)xb1;   // alias: ebuf dead before prop1 writes xb1

    hipMemsetAsync(bCnt, 0, (size_t)MAXNB * 4, stream);

    int echunks = (E + CHUNK - 1) / CHUNK;
    bucket_count_kernel<<<echunks, 256, 0, stream>>>(dst, bCnt, E, NB);
    bucket_scan_kernel<<<1, 256, 0, stream>>>(bCnt, bBase, bCur, offs, NB, N);
    bucket_scatter_kernel<<<echunks, 256, 0, stream>>>(src, dst, bCur, ebuf, E);
    build_norm_kernel<<<NB, 256, 0, stream>>>(ebuf, bBase, offs, norm, N);
    build_csr_kernel<<<NB, 256, 0, stream>>>(ebuf, bBase, offs, norm, csr, N);

    conv_weights_kernel<<<(256 * 128 + 48 * 256 + 255) / 256, 256, 0, stream>>>(W1, W2, W1T, W2T);
    cast_kernel<<<(N * 64 + 255) / 256, 256, 0, stream>>>(feat, xb0, N * 64);

    prop_kernel<<<N, 64, 0, stream>>>(xb0, xb1, ybuf, feat, offs, csr, 1);
    prop_kernel<<<N, 64, 0, stream>>>(xb1, xb0, ybuf, feat, offs, csr, 0);
    prop_kernel<<<N, 64, 0, stream>>>(xb0, xb1, ybuf, feat, offs, csr, 0);

    mlp_kernel<<<(N + 63) / 64, 256, 0, stream>>>(ybuf, W1T, b1, W2T, b2, out, N);
}